// Round 15
// baseline (43.571 us; speedup 1.0000x reference)
//
#include <hip/hip_runtime.h>
#include <cstddef>

#define T_DIM 30000
#define M_DIM 23
#define NJ    92
#define TILE  64       // output timesteps per conv block
#define SUBS  25       // sub LDS stride
#define XP4   377      // reduce LDS pitch in float4
#define WPS   144      // wpadT per-g stride (x in [-16,127])
#define PADC  50       // leading pad (ushorts) per Ycp column -> conv loads 16B-aligned
#define CSTR  30208    // Ycp column stride in ushorts (60416 B, 16B-multiple)
#define CSTR32 (CSTR/2)

typedef short bf16x8 __attribute__((ext_vector_type(8)));
typedef float f32x4  __attribute__((ext_vector_type(4)));

__device__ __forceinline__ unsigned short f2bf(float f) {
    unsigned int u = __float_as_uint(f);
    return (unsigned short)((u + 0x7fffu + ((u >> 16) & 1u)) >> 16);
}

// ---- Kernel B: X (T,1500) fp32 -> Ycp (92 cols x CSTR) bf16 column-major.
// High-TLP (2 rows / 128-thread block) + tiny LDS transpose + XCD-swizzled
// block->t mapping (16 blocks sharing an output line sit on one XCD).
// Pads ([0,50) and [30050,30208) per column) zeroed by blocks 0..91.
__global__ __launch_bounds__(128) void reduce_t(const float* __restrict__ X,
                                                unsigned short* __restrict__ Ycp) {
    __shared__ __align__(16) float4 Xs[2 * XP4];          // 12064 B
    __shared__ unsigned short Ytr[92 * 2];                // 368 B

    const int tid = threadIdx.x;
    const int b   = blockIdx.x;
    const int swb = (b & 7) * 1875 + (b >> 3);            // XCD-contiguous t ranges
    const int tb  = swb * 2;

    const float4* Xg = reinterpret_cast<const float4*>(X) + (size_t)tb * 375;
    #pragma unroll
    for (int it = 0; it < 6; ++it) {
        int i = tid + 128 * it;
        if (i < 750) {
            int r = (i >= 375) ? 1 : 0;
            int pos = i - r * 375;
            Xs[r * XP4 + pos] = Xg[i];
        }
    }
    __syncthreads();

    if (tid < 46) {
        int r = tid / 23;
        int q = tid - 23 * r;
        const float4* row = &Xs[r * XP4];
        float4 s = make_float4(0.f, 0.f, 0.f, 0.f);
        #pragma unroll
        for (int k = 0; k < 16; ++k) {
            float4 v = row[q + 23 * k];
            s.x += v.x; s.y += v.y; s.z += v.z; s.w += v.w;
        }
        if (q < 7) {
            float4 v = row[q + 23 * 16];
            s.x += v.x; s.y += v.y; s.z += v.z; s.w += v.w;
        }
        Ytr[(4 * q + 0) * 2 + r] = f2bf(s.x);
        Ytr[(4 * q + 1) * 2 + r] = f2bf(s.y);
        Ytr[(4 * q + 2) * 2 + r] = f2bf(s.z);
        Ytr[(4 * q + 3) * 2 + r] = f2bf(s.w);
    }
    __syncthreads();

    if (tid < 92) {
        unsigned int v = (unsigned)Ytr[tid * 2] | ((unsigned)Ytr[tid * 2 + 1] << 16);
        reinterpret_cast<unsigned int*>(Ycp)[(size_t)tid * CSTR32 + (PADC + tb) / 2] = v;
    }

    // pad zeroing: block b (< 92) owns column b; 25 lead + 79 tail dwords
    if (b < 92 && tid < 104) {
        unsigned int* col32 = reinterpret_cast<unsigned int*>(Ycp) + (size_t)b * CSTR32;
        int u = (tid < 25) ? tid : (15025 + (tid - 25));
        col32[u] = 0u;
    }
}

// ---- Kernel C: MFMA Toeplitz conv + tree cascade; B-fragments direct from
// global column-major Ycp (no Yt staging, LDS ~9 KB). XCD-swizzled tiles.
__global__ __launch_bounds__(512, 2) void conv_tree_k(
    const unsigned short* __restrict__ Ycp,
    const float* __restrict__ Tau,
    const float* __restrict__ Delta,
    const float* __restrict__ W,
    const float* __restrict__ Vo,
    const float* __restrict__ C,
    const float* __restrict__ Theta,
    float* __restrict__ out)
{
    __shared__ __align__(16) float wpadT[4 * WPS];   // 2304 B
    __shared__ float sub[TILE * SUBS];               // 6400 B
    __shared__ float sTheta[M_DIM];
    __shared__ float sExpC[M_DIM];

    const int tid = threadIdx.x;
    const int bb  = blockIdx.x;
    // bijective XCD swizzle for 469 blocks (q=58, r=5): colocate neighbor tiles
    const int xcd = bb & 7, ii = bb >> 3;
    const int wkid = (xcd < 5) ? (xcd * 59 + ii) : (295 + (xcd - 5) * 58 + ii);
    const int t0  = wkid * TILE;
    const int l   = tid & 63;

    // --- padded weight table: wpadT[g*WPS + (x+16)] = wk(g,x)*W[g], x in [-16,127]
    {
        float eD = __expf(Delta[0]);
        for (int i = tid; i < 4 * WPS; i += 512) {
            int g = i / WPS;
            int x = (i - g * WPS) - 16;
            float val = 0.f;
            if (x >= 0 && x <= 100) {
                float tt  = fmaxf((float)x - eD, 0.f);
                float tau = __expf(Tau[g]);
                float tf  = tt / tau;
                float fast = tf * __expf(-tf);
                float kv;
                if (g < 2) {
                    float ts = tt / (tau * 2.8f + 10.4f);
                    kv = (fast + ts * __expf(-ts) * 0.3f) * (1.0f / 1.3f);
                } else {
                    kv = fast;
                }
                val = kv * W[g];
            }
            wpadT[i] = val;
        }
    }
    if (tid < M_DIM) {
        sTheta[tid] = Theta[tid];
        sExpC[tid]  = __expf(C[tid]);
    }
    __syncthreads();

    // --- A-fragments from wpadT. frag (g,kk): lane l elem j ->
    // A_g[i,k] = Wpad_g[k-i], i = l&15, k = kk*32 + (l>>4)*8 + j.
    const int n  = l & 15;
    const int kq = (l >> 4) << 3;
    uint4 af[16];
    #pragma unroll
    for (int g = 0; g < 4; ++g) {
        const float* wp = &wpadT[g * WPS + 16 - n + kq];
        #pragma unroll
        for (int kk = 0; kk < 4; ++kk) {
            const float* wk8 = wp + kk * 32;
            unsigned int d[4];
            #pragma unroll
            for (int p = 0; p < 4; ++p) {
                unsigned short lo = f2bf(wk8[2 * p]);
                unsigned short hi = f2bf(wk8[2 * p + 1]);
                d[p] = (unsigned)lo | ((unsigned)hi << 16);
            }
            af[g * 4 + kk] = make_uint4(d[0], d[1], d[2], d[3]);
        }
    }

    const int wave = tid >> 6;            // 0..7
    const int dt   = (wave & 3) * 16;     // t-subtile
    const int nt   = wave >> 2;           // m-tile
    const int m    = nt * 16 + n;
    const bool mvalid = (m < M_DIM);
    const int mc   = mvalid ? m : 0;

    // --- B direct from global: col j, rows t0-50+dt+kq+kk*32 (+PADC offset = 0)
    f32x4 acc = {0.f, 0.f, 0.f, 0.f};
    #pragma unroll
    for (int g = 0; g < 4; ++g) {
        int a  = (3 * ((g - mc) & 3)) & 3;
        int j  = mc + 23 * a;                 // original column index, 0..91
        const unsigned short* colp = Ycp + (size_t)j * CSTR + t0 + dt + kq;

        bf16x8 b0 = *reinterpret_cast<const bf16x8*>(colp);
        acc = __builtin_amdgcn_mfma_f32_16x16x32_bf16(__builtin_bit_cast(bf16x8, af[g*4+0]), b0, acc, 0, 0, 0);
        bf16x8 b1 = *reinterpret_cast<const bf16x8*>(colp + 32);
        acc = __builtin_amdgcn_mfma_f32_16x16x32_bf16(__builtin_bit_cast(bf16x8, af[g*4+1]), b1, acc, 0, 0, 0);
        bf16x8 b2 = *reinterpret_cast<const bf16x8*>(colp + 64);
        acc = __builtin_amdgcn_mfma_f32_16x16x32_bf16(__builtin_bit_cast(bf16x8, af[g*4+2]), b2, acc, 0, 0, 0);
        bf16x8 b3 = *reinterpret_cast<const bf16x8*>(colp + 96);
        acc = __builtin_amdgcn_mfma_f32_16x16x32_bf16(__builtin_bit_cast(bf16x8, af[g*4+3]), b3, acc, 0, 0, 0);
    }

    // epilogue: D col = l&15 (m), row = (l>>4)*4 + r -> t_local = dt + row
    if (mvalid) {
        int i0 = (l >> 4) * 4;
        #pragma unroll
        for (int r = 0; r < 4; ++r)
            sub[(dt + i0 + r) * SUBS + m] = acc[r];
    }
    __syncthreads();

    // --- tree cascade, one thread per timestep
    if (tid < TILE) {
        int t = t0 + tid;
        if (t < T_DIM) {
            const float* s = &sub[tid * SUBS];
            float o[M_DIM];
            #pragma unroll
            for (int mm = 11; mm < 23; ++mm) {
                float x = s[mm] - sTheta[mm];
                o[mm] = sExpC[mm] / (1.f + __expf(-x));
            }
            #pragma unroll
            for (int rr = 10; rr >= 0; --rr) {
                float x = s[rr] + o[2 * rr + 1] + o[2 * rr + 2] - sTheta[rr];
                o[rr] = sExpC[rr] / (1.f + __expf(-x));
            }
            out[t] = o[0] + Vo[0];
        }
    }
}

extern "C" void kernel_launch(void* const* d_in, const int* in_sizes, int n_in,
                              void* d_out, int out_size, void* d_ws, size_t ws_size,
                              hipStream_t stream) {
    const float* X     = (const float*)d_in[0];
    const float* Vo    = (const float*)d_in[1];
    const float* Tau   = (const float*)d_in[2];
    const float* Delta = (const float*)d_in[3];
    const float* W     = (const float*)d_in[4];
    const float* C     = (const float*)d_in[5];
    const float* Theta = (const float*)d_in[6];
    float* out = (float*)d_out;
    unsigned short* Ycp = (unsigned short*)d_ws;   // 92 * 30208 bf16 = 5.56 MB

    reduce_t<<<T_DIM / 2, 128, 0, stream>>>(X, Ycp);
    conv_tree_k<<<469, 512, 0, stream>>>(Ycp, Tau, Delta, W, Vo, C, Theta, out);
}